// Round 11
// baseline (43.360 us; speedup 1.0000x reference)
//
#include <hip/hip_runtime.h>
#include <hip/hip_bf16.h>
#include <hip/hip_fp8.h>

// Problem constants (fixed by setup_inputs): B=4096, d=128, M=8192, C=16
#define B_ROWS 4096
#define D_K    128
#define M_ROWS 8192
#define N_TOT  12288   // B_ROWS + M_ROWS
#define NCHUNK 32      // j-chunks (grid.x of sim), 384 cols each
#define JT_PER_CHUNK 6 // 6 tiles of 64 cols: 32*6*64 = 12288 = N_TOT
#define JCOLS  64      // cols per tile
#define NCLS   16
#define NRMB   384     // nrm blocks, 32 rows each
#define NBIB   128     // in-batch nrm blocks (4096/32) = #partS partials

typedef __attribute__((ext_vector_type(4))) int   intx4;
typedef __attribute__((ext_vector_type(8))) int   intx8;
typedef __attribute__((ext_vector_type(4))) float floatx4;

__device__ __forceinline__ float fp8_to_f32(unsigned char b) {
    __hip_fp8_e4m3 h; h.__x = b; return float(h);
}

// ---------------------------------------------------------------------------
// Kernel 1: fused normalize + per-block class-sum partials.
// 384 blocks x 256 thr; block owns 32 rows (8 per wave, wave-per-row inner).
// All 8 row loads issued up front (16 VGPRs) for latency overlap.
// In-batch blocks (0..127) additionally accumulate their own 32 rows into an
// LDS S-partial (LDS atomics: lanes hit distinct addresses within a wave)
// and write partS[blk][2048] with plain coalesced stores. NO global atomics.
// ---------------------------------------------------------------------------
__global__ __launch_bounds__(256) void nrmS_kernel(
    const float* __restrict__ f, const float* __restrict__ fneg,
    const int* __restrict__ labels, unsigned char* __restrict__ G8,
    float* __restrict__ partS)
{
    const int tid  = threadIdx.x;
    const int wave = tid >> 6;
    const int lane = tid & 63;
    const int blk  = blockIdx.x;
    const int rbase = blk * 32 + wave * 8;

    float2 v[8];
    #pragma unroll
    for (int r = 0; r < 8; ++r) {
        const int row = rbase + r;
        const float* src = (row < B_ROWS)
            ? (f + (size_t)row * D_K) : (fneg + (size_t)(row - B_ROWS) * D_K);
        v[r] = *reinterpret_cast<const float2*>(src + lane * 2);
    }

    unsigned short q[8];
    int cls[8];
    #pragma unroll
    for (int r = 0; r < 8; ++r) {
        const int row = rbase + r;
        float ss = v[r].x * v[r].x + v[r].y * v[r].y;
        #pragma unroll
        for (int m = 1; m < 64; m <<= 1) ss += __shfl_xor(ss, m, 64);
        const float scale = 1.0f / fmaxf(sqrtf(ss), 1e-8f);  // 1/max(||x||,EPS)
        __hip_fp8_e4m3 q0(v[r].x * scale);
        __hip_fp8_e4m3 q1(v[r].y * scale);
        const unsigned short pk =
            (unsigned short)q0.__x | ((unsigned short)q1.__x << 8);
        *reinterpret_cast<unsigned short*>(G8 + (size_t)row * D_K + lane * 2) = pk;
        q[r]   = pk;
        cls[r] = (row < B_ROWS) ? labels[row] : 0;
    }

    if (blk < NBIB) {
        __shared__ float Sp[NCLS * D_K];
        for (int k = tid; k < NCLS * D_K; k += 256) Sp[k] = 0.f;
        __syncthreads();
        #pragma unroll
        for (int r = 0; r < 8; ++r) {
            atomicAdd(&Sp[cls[r] * D_K + 2 * lane],     fp8_to_f32(q[r] & 0xff));
            atomicAdd(&Sp[cls[r] * D_K + 2 * lane + 1], fp8_to_f32(q[r] >> 8));
        }
        __syncthreads();
        #pragma unroll
        for (int k = 0; k < 8; ++k)
            partS[(size_t)blk * (NCLS * D_K) + tid * 8 + k] = Sp[tid * 8 + k];
    }
}

// ---------------------------------------------------------------------------
// Kernel 2: branch-free exp-sum GEMM via MX-FP8 K=128 (R7 geometry — best
// measured) + service blocks. Grid (32, 33):
//   it < 32 : sim. Block tile 128i x 384j (6 double-buffered 64-col tiles),
//             4 waves, wave 32i x 64j; reg-staged swizzled LDS (R5-R7
//             verified); 2 MFMAs + 8 exp-adds per fragment.
//   it == 32: jc<16 -> reduce partS (128 partials) into S[jc*128..+128);
//             jc==16 -> label histogram + out=0;  jc>16 -> exit.
// Service outputs (S, hist, out) are consumed only by fin (kernel boundary).
// A/B lane->byte mappings identical, so any K-permutation cancels in G*G^T.
// C/D: col(j) = lane&15, row(i) = (lane>>4)*4 + reg (shape-determined).
// ---------------------------------------------------------------------------
__global__ __launch_bounds__(256, 4) void sim_kernel(
    const unsigned char* __restrict__ G8, const int* __restrict__ labels,
    const float* __restrict__ partS, float* __restrict__ part_d,
    float* __restrict__ S, int* __restrict__ hist, float* __restrict__ out)
{
    __shared__ unsigned char Bs[2][JCOLS * D_K];   // 2 x 8KB

    const int tid = threadIdx.x;

    if (blockIdx.y == 32) {        // ---- service blocks ----
        const int role = blockIdx.x;
        if (role < 16) {
            if (tid < 128) {
                const int e = role * 128 + tid;
                float s = 0.f;
                for (int b = 0; b < NBIB; ++b)
                    s += partS[(size_t)b * (NCLS * D_K) + e];
                S[e] = s;
            }
        } else if (role == 16) {
            __shared__ int lh[NCLS];
            if (tid < NCLS) lh[tid] = 0;
            __syncthreads();
            for (int j = tid; j < B_ROWS; j += 256) atomicAdd(&lh[labels[j]], 1);
            __syncthreads();
            if (tid < NCLS) hist[tid] = lh[tid];
            if (tid == 0) out[0] = 0.f;
        }
        return;
    }

    const int jc   = blockIdx.x;          // 0..31
    const int it   = blockIdx.y;          // 0..31
    const int wave = tid >> 6;            // 0..3 : i-quarter
    const int lane = tid & 63;
    const int i0   = it * 128 + wave * 32;

    const int r16 = lane & 15;
    const int grp = lane >> 4;            // 0..3

    // resident A fragments [a]: rows i0 + a*16 + r16, bytes grp*32..+31
    const unsigned char* Abase = G8 + (size_t)(i0 + r16) * D_K + grp * 32;
    intx8 afr[2];
    #pragma unroll
    for (int a = 0; a < 2; ++a)
        afr[a] = *reinterpret_cast<const intx8*>(Abase + (size_t)a * 16 * D_K);

    float dsum[2][4];
    #pragma unroll
    for (int a = 0; a < 2; ++a)
        #pragma unroll
        for (int r = 0; r < 4; ++r) dsum[a][r] = 0.f;

    // staging: 8KB tile, 256 thr x 16B x 2 rounds. LDS linear byte
    // p = s*4096 + tid*16 -> row = s*32 + tid/8, slot = tid&7;
    // source granule pre-swizzled: gran = slot ^ (row&7).
    int srcoff[2];
    #pragma unroll
    for (int s = 0; s < 2; ++s) {
        const int row  = s * 32 + (tid >> 3);
        const int gran = (tid & 7) ^ (row & 7);
        srcoff[s] = row * D_K + gran * 16;
    }

    intx4 streg[2];
    {   // prologue: tile 0 -> buf 0
        const unsigned char* src =
            G8 + (size_t)(jc * JT_PER_CHUNK) * JCOLS * D_K;
        #pragma unroll
        for (int s = 0; s < 2; ++s)
            streg[s] = *reinterpret_cast<const intx4*>(src + srcoff[s]);
        #pragma unroll
        for (int s = 0; s < 2; ++s)
            *reinterpret_cast<intx4*>(&Bs[0][0] + s * 4096 + tid * 16) =
                streg[s];
    }

    for (int t = 0; t < JT_PER_CHUNK; ++t) {
        const int cur = t & 1;
        __syncthreads();   // buf[cur] written & visible; buf[cur^1] reads done

        if (t + 1 < JT_PER_CHUNK) {
            const unsigned char* src =
                G8 + (size_t)(jc * JT_PER_CHUNK + t + 1) * JCOLS * D_K;
            #pragma unroll
            for (int s = 0; s < 2; ++s)
                streg[s] = *reinterpret_cast<const intx4*>(src + srcoff[s]);
        }

        floatx4 acc[2][4];
        #pragma unroll
        for (int a = 0; a < 2; ++a)
            #pragma unroll
            for (int b = 0; b < 4; ++b)
                acc[a][b] = (floatx4){0.f, 0.f, 0.f, 0.f};

        const unsigned char* base = &Bs[cur][0];
        #pragma unroll
        for (int b = 0; b < 4; ++b) {
            const int jloc = b * 16 + r16;
            const int sw   = jloc & 7;
            intx4 lo = *reinterpret_cast<const intx4*>(
                base + jloc * D_K + ((2 * grp)     ^ sw) * 16);
            intx4 hi = *reinterpret_cast<const intx4*>(
                base + jloc * D_K + ((2 * grp + 1) ^ sw) * 16);
            intx8 bfr;
            #pragma unroll
            for (int e = 0; e < 4; ++e) { bfr[e] = lo[e]; bfr[e + 4] = hi[e]; }
            #pragma unroll
            for (int a = 0; a < 2; ++a)
                acc[a][b] = __builtin_amdgcn_mfma_scale_f32_16x16x128_f8f6f4(
                    afr[a], bfr, acc[a][b], 0, 0,
                    0, 0x7F7F7F7F, 0, 0x7F7F7F7F);   // unity scales
        }

        // branch-free epilogue: exp-sum everything (self handled in fin)
        #pragma unroll
        for (int a = 0; a < 2; ++a)
            #pragma unroll
            for (int r = 0; r < 4; ++r) {
                float s0 = __expf(acc[a][0][r]) + __expf(acc[a][1][r]);
                float s1 = __expf(acc[a][2][r]) + __expf(acc[a][3][r]);
                dsum[a][r] += s0 + s1;
            }

        if (t + 1 < JT_PER_CHUNK) {
            #pragma unroll
            for (int s = 0; s < 2; ++s)
                *reinterpret_cast<intx4*>(
                    &Bs[cur ^ 1][0] + s * 4096 + tid * 16) = streg[s];
        }
    }

    // 16-lane (column-group) reduce
    #pragma unroll
    for (int a = 0; a < 2; ++a)
        #pragma unroll
        for (int r = 0; r < 4; ++r) {
            #pragma unroll
            for (int m = 1; m < 16; m <<= 1)
                dsum[a][r] += __shfl_xor(dsum[a][r], m, 64);
        }
    if (r16 == 0) {
        #pragma unroll
        for (int a = 0; a < 2; ++a)
            #pragma unroll
            for (int r = 0; r < 4; ++r)
                part_d[(size_t)(i0 + a * 16 + grp * 4 + r) * NCHUNK + jc] =
                    dsum[a][r];
    }
}

// ---------------------------------------------------------------------------
// Kernel 3: finalize. 64 blocks x 4 waves; each wave owns 16 rows.
// Per row: denom = sum(32 partials) - exp(selfdot);
// psum = <g_i, S[lab]> - selfdot; loss = log(denom) - psum/npos.
// Block reduce -> atomicAdd(out, mean part). 64 single-address atomics.
// ---------------------------------------------------------------------------
__global__ __launch_bounds__(256) void fin_kernel(
    const unsigned char* __restrict__ G8, const float* __restrict__ part_d,
    const float* __restrict__ S, const int* __restrict__ labels,
    const int* __restrict__ hist, float* __restrict__ out)
{
    const int tid  = threadIdx.x;
    const int wave = tid >> 6;
    const int lane = tid & 63;

    float lsum = 0.f;
    #pragma unroll 2
    for (int rr = 0; rr < 16; ++rr) {
        const int i   = (blockIdx.x * 4 + wave) * 16 + rr;
        const int lab = labels[i];
        float pd = (lane < NCHUNK) ? part_d[(size_t)i * NCHUNK + lane] : 0.f;
        const unsigned char* gr = G8 + (size_t)i * D_K + lane * 2;
        const float f0 = fp8_to_f32(gr[0]);
        const float f1 = fp8_to_f32(gr[1]);
        float2 sv = *reinterpret_cast<const float2*>(S + lab * D_K + lane * 2);
        float self = f0 * f0 + f1 * f1;
        float sp   = f0 * sv.x + f1 * sv.y;
        #pragma unroll
        for (int m = 1; m < 64; m <<= 1) {
            pd   += __shfl_xor(pd, m, 64);
            self += __shfl_xor(self, m, 64);
            sp   += __shfl_xor(sp, m, 64);
        }
        if (lane == 0) {
            const float npos  = (float)(hist[lab] - 1);
            const float denom = pd - __expf(self);
            lsum += __logf(denom) - (sp - self) / npos;
        }
    }
    __shared__ float w4[4];
    if (lane == 0) w4[wave] = lsum;
    __syncthreads();
    if (tid == 0)
        atomicAdd(out, (w4[0] + w4[1] + w4[2] + w4[3]) * (1.0f / (float)B_ROWS));
}

// ---------------------------------------------------------------------------
extern "C" void kernel_launch(void* const* d_in, const int* in_sizes, int n_in,
                              void* d_out, int out_size, void* d_ws, size_t ws_size,
                              hipStream_t stream) {
    const float* f      = (const float*)d_in[0];
    const float* fneg   = (const float*)d_in[1];
    const int*   labels = (const int*)d_in[2];
    float*       out    = (float*)d_out;

    char* ws = (char*)d_ws;
    // Workspace layout (bytes):
    //   G8     : 12288*128     = 1,572,864
    //   part_d : 4096*32*4     =   524,288
    //   partS  : 128*2048*4    = 1,048,576
    //   S      : 16*128*4      =     8,192
    //   hist   : 16*4
    unsigned char* G8     = (unsigned char*)(ws);
    float*         part_d = (float*)(ws + 1572864);
    float*         partS  = (float*)(ws + 1572864 + 524288);
    float*         S      = (float*)(ws + 1572864 + 524288 + 1048576);
    int*           hist   = (int*)(ws + 1572864 + 524288 + 1048576 + 8192);

    nrmS_kernel<<<NRMB, 256, 0, stream>>>(f, fneg, labels, G8, partS);

    dim3 gridS(NCHUNK, 33);   // (32, 33): 1024 sim blocks + 17 service blocks
    sim_kernel<<<gridS, 256, 0, stream>>>(G8, labels, partS, part_d, S, hist, out);

    fin_kernel<<<64, 256, 0, stream>>>(G8, part_d, S, labels, hist, out);
}

// Round 13
// 36.166 us; speedup vs baseline: 1.1989x; 1.1989x over previous
//
#include <hip/hip_runtime.h>
#include <hip/hip_bf16.h>
#include <hip/hip_fp8.h>

// Problem constants (fixed by setup_inputs): B=4096, d=128, M=8192, C=16
#define B_ROWS 4096
#define D_K    128
#define M_ROWS 8192
#define N_TOT  12288   // B_ROWS + M_ROWS
#define NCHUNK 32      // j-chunks (grid.x of sim), 384 cols each
#define JT_PER_CHUNK 6 // 6 tiles of 64 cols: 32*6*64 = 12288 = N_TOT (coverage!)
#define JCOLS  64      // cols per tile
#define NCLS   16

typedef __attribute__((ext_vector_type(4))) int   intx4;
typedef __attribute__((ext_vector_type(8))) int   intx8;
typedef __attribute__((ext_vector_type(4))) float floatx4;

__device__ __forceinline__ float fp8_to_f32(unsigned char b) {
    __hip_fp8_e4m3 h; h.__x = b; return float(h);
}

// ---------------------------------------------------------------------------
// Kernel 1 (R7-verbatim + A8 store): normalize rows of f / f_neg into OCP
// fp8-e4m3 G8[N_TOT][128]; in-batch rows additionally stored pre-scaled by
// log2(e) into A8[B_ROWS][128] (sim's A operand -> exp2 epilogue, saves one
// VALU mul per output element). One wave per row. Block 0 zeros S/hist/out.
// ---------------------------------------------------------------------------
__global__ __launch_bounds__(256) void nrm_kernel(
    const float* __restrict__ f, const float* __restrict__ fneg,
    unsigned char* __restrict__ G8, unsigned char* __restrict__ A8,
    float* __restrict__ S, int* __restrict__ hist, float* __restrict__ out)
{
    const int tid  = threadIdx.x;
    const int wave = tid >> 6;
    const int lane = tid & 63;
    const int row  = blockIdx.x * 4 + wave;           // grid exact: 3072*4
    if (blockIdx.x == 0) {
        #pragma unroll
        for (int k = 0; k < 8; ++k) S[tid + k * 256] = 0.f;
        if (tid < NCLS) hist[tid] = 0;
        if (tid == 0) out[0] = 0.f;
    }
    const float* src = (row < B_ROWS) ? (f + (size_t)row * D_K)
                                      : (fneg + (size_t)(row - B_ROWS) * D_K);
    float2 v = *reinterpret_cast<const float2*>(src + lane * 2);
    float ss = v.x * v.x + v.y * v.y;
    #pragma unroll
    for (int m = 1; m < 64; m <<= 1) ss += __shfl_xor(ss, m, 64);
    const float scale = 1.0f / fmaxf(sqrtf(ss), 1e-8f);   // 1/max(||x||, EPS)
    __hip_fp8_e4m3 q0(v.x * scale);
    __hip_fp8_e4m3 q1(v.y * scale);
    const unsigned short pk =
        (unsigned short)q0.__x | ((unsigned short)q1.__x << 8);
    *reinterpret_cast<unsigned short*>(G8 + (size_t)row * D_K + lane * 2) = pk;
    if (row < B_ROWS) {
        const float s2 = scale * 1.44269504f;             // * log2(e)
        __hip_fp8_e4m3 a0(v.x * s2);
        __hip_fp8_e4m3 a1(v.y * s2);
        const unsigned short pa =
            (unsigned short)a0.__x | ((unsigned short)a1.__x << 8);
        *reinterpret_cast<unsigned short*>(A8 + (size_t)row * D_K + lane * 2) = pa;
    }
}

// ---------------------------------------------------------------------------
// Kernel 2: branch-free exp-sum GEMM via MX-FP8 K=128 (R7 geometry — best
// measured, 37.1us) + csum service blocks. Grid (32, 36):
//   y < 32 : sim. Block tile 128i x 384j (6 double-buffered 64-col tiles),
//            4 waves, wave 32i x 64j; reg-staged swizzled LDS (R5-R7
//            verified); A from A8 (log2e-scaled) -> exp2f epilogue.
//   y >= 32: svc = (y-32)*32 + x in 0..127 — EXACT port of R7's 128-block
//            csum (stripe = svc&31 row-block of 128, dc = svc>>5 dim-chunk
//            of 32; LDS partials reusing Bs storage; global atomicAdd
//            merge into S + hist). Dispatched last -> runs in sim's tail.
// A/B lane->byte mappings identical, so any K-permutation cancels in G*G^T.
// C/D: col(j) = lane&15, row(i) = (lane>>4)*4 + reg (shape-determined).
// ---------------------------------------------------------------------------
__global__ __launch_bounds__(256, 4) void sim_kernel(
    const unsigned char* __restrict__ G8, const unsigned char* __restrict__ A8,
    const int* __restrict__ labels, float* __restrict__ part_d,
    float* __restrict__ S, int* __restrict__ hist)
{
    __shared__ unsigned char Bs[2][JCOLS * D_K];   // 2 x 8KB

    const int tid = threadIdx.x;

    if (blockIdx.y >= 32) {        // ---- csum service blocks (R7 csum port) ----
        const int svc    = (blockIdx.y - 32) * NCHUNK + blockIdx.x;  // 0..127
        const int stripe = svc & 31;   // 128-row stripe
        const int dc     = svc >> 5;   // 0..3 : 32-dim chunk
        float* Sp = (float*)&Bs[0][0];            // 2KB of the 16KB Bs
        int*   lh = (int*)(Sp + NCLS * 32);       // +64B
        for (int k = tid; k < NCLS * 32; k += 256) Sp[k] = 0.f;
        if (tid < NCLS) lh[tid] = 0;
        __syncthreads();

        const int j0 = stripe * 128;
        if (dc == 0 && tid < 128) atomicAdd(&lh[labels[j0 + tid]], 1);

        const int d = tid & 31;
        const int w = tid >> 5;               // 0..7 row-walkers
        for (int jj = w; jj < 128; jj += 8) {
            const int j = j0 + jj;
            const int c = labels[j];
            atomicAdd(&Sp[c * 32 + d],
                      fp8_to_f32(G8[(size_t)j * D_K + dc * 32 + d]));
        }
        __syncthreads();
        for (int k = tid; k < NCLS * 32; k += 256)
            atomicAdd(&S[(k >> 5) * D_K + dc * 32 + (k & 31)], Sp[k]);
        if (dc == 0 && tid < NCLS) atomicAdd(&hist[tid], lh[tid]);
        return;
    }

    const int jc   = blockIdx.x;          // 0..31
    const int it   = blockIdx.y;          // 0..31
    const int wave = tid >> 6;            // 0..3 : i-quarter
    const int lane = tid & 63;
    const int i0   = it * 128 + wave * 32;

    const int r16 = lane & 15;
    const int grp = lane >> 4;            // 0..3

    // resident A fragments [a] from A8 (log2e-scaled): rows i0 + a*16 + r16
    const unsigned char* Abase = A8 + (size_t)(i0 + r16) * D_K + grp * 32;
    intx8 afr[2];
    #pragma unroll
    for (int a = 0; a < 2; ++a)
        afr[a] = *reinterpret_cast<const intx8*>(Abase + (size_t)a * 16 * D_K);

    float dsum[2][4];
    #pragma unroll
    for (int a = 0; a < 2; ++a)
        #pragma unroll
        for (int r = 0; r < 4; ++r) dsum[a][r] = 0.f;

    // staging: 8KB tile, 256 thr x 16B x 2 rounds. LDS linear byte
    // p = s*4096 + tid*16 -> row = s*32 + tid/8, slot = tid&7;
    // source granule pre-swizzled: gran = slot ^ (row&7).
    int srcoff[2];
    #pragma unroll
    for (int s = 0; s < 2; ++s) {
        const int row  = s * 32 + (tid >> 3);
        const int gran = (tid & 7) ^ (row & 7);
        srcoff[s] = row * D_K + gran * 16;
    }

    intx4 streg[2];
    {   // prologue: tile 0 -> buf 0
        const unsigned char* src =
            G8 + (size_t)(jc * JT_PER_CHUNK) * JCOLS * D_K;
        #pragma unroll
        for (int s = 0; s < 2; ++s)
            streg[s] = *reinterpret_cast<const intx4*>(src + srcoff[s]);
        #pragma unroll
        for (int s = 0; s < 2; ++s)
            *reinterpret_cast<intx4*>(&Bs[0][0] + s * 4096 + tid * 16) =
                streg[s];
    }

    for (int t = 0; t < JT_PER_CHUNK; ++t) {
        const int cur = t & 1;
        __syncthreads();   // buf[cur] written & visible; buf[cur^1] reads done

        if (t + 1 < JT_PER_CHUNK) {
            const unsigned char* src =
                G8 + (size_t)(jc * JT_PER_CHUNK + t + 1) * JCOLS * D_K;
            #pragma unroll
            for (int s = 0; s < 2; ++s)
                streg[s] = *reinterpret_cast<const intx4*>(src + srcoff[s]);
        }

        floatx4 acc[2][4];
        #pragma unroll
        for (int a = 0; a < 2; ++a)
            #pragma unroll
            for (int b = 0; b < 4; ++b)
                acc[a][b] = (floatx4){0.f, 0.f, 0.f, 0.f};

        const unsigned char* base = &Bs[cur][0];
        #pragma unroll
        for (int b = 0; b < 4; ++b) {
            const int jloc = b * 16 + r16;
            const int sw   = jloc & 7;
            intx4 lo = *reinterpret_cast<const intx4*>(
                base + jloc * D_K + ((2 * grp)     ^ sw) * 16);
            intx4 hi = *reinterpret_cast<const intx4*>(
                base + jloc * D_K + ((2 * grp + 1) ^ sw) * 16);
            intx8 bfr;
            #pragma unroll
            for (int e = 0; e < 4; ++e) { bfr[e] = lo[e]; bfr[e + 4] = hi[e]; }
            #pragma unroll
            for (int a = 0; a < 2; ++a)
                acc[a][b] = __builtin_amdgcn_mfma_scale_f32_16x16x128_f8f6f4(
                    afr[a], bfr, acc[a][b], 0, 0,
                    0, 0x7F7F7F7F, 0, 0x7F7F7F7F);   // unity scales
        }

        // branch-free epilogue: acc = log2e*sim -> exp2 (native v_exp_f32)
        #pragma unroll
        for (int a = 0; a < 2; ++a)
            #pragma unroll
            for (int r = 0; r < 4; ++r) {
                float s0 = exp2f(acc[a][0][r]) + exp2f(acc[a][1][r]);
                float s1 = exp2f(acc[a][2][r]) + exp2f(acc[a][3][r]);
                dsum[a][r] += s0 + s1;
            }

        if (t + 1 < JT_PER_CHUNK) {
            #pragma unroll
            for (int s = 0; s < 2; ++s)
                *reinterpret_cast<intx4*>(
                    &Bs[cur ^ 1][0] + s * 4096 + tid * 16) = streg[s];
        }
    }

    // 16-lane (column-group) reduce
    #pragma unroll
    for (int a = 0; a < 2; ++a)
        #pragma unroll
        for (int r = 0; r < 4; ++r) {
            #pragma unroll
            for (int m = 1; m < 16; m <<= 1)
                dsum[a][r] += __shfl_xor(dsum[a][r], m, 64);
        }
    if (r16 == 0) {
        #pragma unroll
        for (int a = 0; a < 2; ++a)
            #pragma unroll
            for (int r = 0; r < 4; ++r)
                part_d[(size_t)(i0 + a * 16 + grp * 4 + r) * NCHUNK + jc] =
                    dsum[a][r];
    }
}

// ---------------------------------------------------------------------------
// Kernel 3 (R7-verbatim): finalize. 128 blocks x 4 waves; each wave 8 rows.
// Per row: denom = sum(32 partials) - exp(selfdot);
// psum = <g_i, S[lab]> - selfdot; loss = log(denom) - psum/npos.
// Block reduce -> atomicAdd(out, mean part).
// ---------------------------------------------------------------------------
__global__ __launch_bounds__(256) void fin_kernel(
    const unsigned char* __restrict__ G8, const float* __restrict__ part_d,
    const float* __restrict__ S, const int* __restrict__ labels,
    const int* __restrict__ hist, float* __restrict__ out)
{
    const int tid  = threadIdx.x;
    const int wave = tid >> 6;
    const int lane = tid & 63;

    float lsum = 0.f;
    #pragma unroll 2
    for (int rr = 0; rr < 8; ++rr) {
        const int i   = (blockIdx.x * 4 + wave) * 8 + rr;
        const int lab = labels[i];
        float pd = (lane < NCHUNK) ? part_d[(size_t)i * NCHUNK + lane] : 0.f;
        const unsigned char* gr = G8 + (size_t)i * D_K + lane * 2;
        const float f0 = fp8_to_f32(gr[0]);
        const float f1 = fp8_to_f32(gr[1]);
        float2 sv = *reinterpret_cast<const float2*>(S + lab * D_K + lane * 2);
        float self = f0 * f0 + f1 * f1;
        float sp   = f0 * sv.x + f1 * sv.y;
        #pragma unroll
        for (int m = 1; m < 64; m <<= 1) {
            pd   += __shfl_xor(pd, m, 64);
            self += __shfl_xor(self, m, 64);
            sp   += __shfl_xor(sp, m, 64);
        }
        if (lane == 0) {
            const float npos  = (float)(hist[lab] - 1);
            const float denom = pd - __expf(self);
            lsum += __logf(denom) - (sp - self) / npos;
        }
    }
    __shared__ float w4[4];
    if (lane == 0) w4[wave] = lsum;
    __syncthreads();
    if (tid == 0)
        atomicAdd(out, (w4[0] + w4[1] + w4[2] + w4[3]) * (1.0f / (float)B_ROWS));
}

// ---------------------------------------------------------------------------
extern "C" void kernel_launch(void* const* d_in, const int* in_sizes, int n_in,
                              void* d_out, int out_size, void* d_ws, size_t ws_size,
                              hipStream_t stream) {
    const float* f      = (const float*)d_in[0];
    const float* fneg   = (const float*)d_in[1];
    const int*   labels = (const int*)d_in[2];
    float*       out    = (float*)d_out;

    char* ws = (char*)d_ws;
    // Workspace layout (bytes):
    //   G8     : 12288*128   = 1,572,864
    //   A8     : 4096*128    =   524,288
    //   part_d : 4096*32*4   =   524,288
    //   S      : 16*128*4    =     8,192
    //   hist   : 16*4
    unsigned char* G8     = (unsigned char*)(ws);
    unsigned char* A8     = (unsigned char*)(ws + 1572864);
    float*         part_d = (float*)(ws + 1572864 + 524288);
    float*         S      = (float*)(ws + 1572864 + 524288 + 524288);
    int*           hist   = (int*)(ws + 1572864 + 524288 + 524288 + 8192);

    nrm_kernel<<<N_TOT / 4, 256, 0, stream>>>(f, fneg, G8, A8, S, hist, out);

    dim3 gridS(NCHUNK, 36);   // (32,36): 1024 sim blocks + 128 csum svc blocks
    sim_kernel<<<gridS, 256, 0, stream>>>(G8, A8, labels, part_d, S, hist);

    fin_kernel<<<128, 256, 0, stream>>>(G8, part_d, S, labels, hist, out);
}